// Round 11
// baseline (214.694 us; speedup 1.0000x reference)
//
#include <hip/hip_runtime.h>
#include <cstddef>

#define NF 8
#define NT 16384
#define ND 64
#define NK 512
#define NDK (ND * NK)      // 32768
#define NFN (NF * NT)      // 131072
#define MARGIN 0.125f

typedef __attribute__((ext_vector_type(8))) short bf16x8;
typedef __attribute__((ext_vector_type(4))) float f32x4;
typedef unsigned int uint32;
typedef unsigned short ushort16;

// ---- workspace layout (float units) ----
static const size_t WS_CNT   = 0;        // counts      : 4096
static const size_t WS_LOSS  = 4096;     // loss accum  : 1
static const size_t WS_FLAGC = 4097;     // flag count  : 1 int
static const size_t WS_T     = 4112;     // tsq + 1024  : 4096
static const size_t WS_SM    = 8208;     // smoothed    : 4096
static const size_t WS_OFFS  = 12304;    // offsets     : 4096 ints
static const size_t WS_CUR   = 16400;    // cursors     : 4096 ints
static const size_t WS_ENC   = 20496;    // enc idx     : NFN ints
static const size_t WS_SORT  = 151568;   // sorted tok  : NFN ints
static const size_t WS_FLAGL = 282640;   // flag list   : NFN ints
static const size_t WS_WTH   = 413712;   // w^T hi bf16 : 131072 floats
static const size_t WS_WTL   = 544784;   // w^T lo bf16 : 131072 floats
static const size_t WS_WT    = 675856;   // w^T f32 [f,k,d] : 262144 floats
static const size_t WS_DW    = 938000;   // dw accum    : 262144 floats

// ---- output layout (float units) ----
static const size_t LOSS_OFF = (size_t)NF * NT * ND;        // 8388608
static const size_t NEWW_OFF = LOSS_OFF + 1;                // 8388609
static const size_t NCS_OFF  = NEWW_OFF + (size_t)NF * NDK; // 8650753
static const size_t NEMA_OFF = NCS_OFF + (size_t)NF * NK;   // 8654849

__device__ inline uint32 bfrne(float f) {   // RNE bf16, as hi-16 bits of f32
    uint32 u = __float_as_uint(f);
    return (u + 0x7FFFu + ((u >> 16) & 1u)) & 0xFFFF0000u;
}
__device__ inline uint32 umin_(uint32 a, uint32 b) { return a < b ? a : b; }
__device__ inline uint32 umax_(uint32 a, uint32 b) { return a > b ? a : b; }

// ============ kernel A: W -> wt_hi/wt_lo bf16 [f,k,d] + wT f32 + tsq+1024 ============
__global__ __launch_bounds__(256) void vq_prep_w(const float* __restrict__ w,
                                                 ushort16* __restrict__ wth,
                                                 ushort16* __restrict__ wtl,
                                                 float* __restrict__ wT,
                                                 float* __restrict__ tsq) {
    int g = blockIdx.x * 256 + threadIdx.x;   // f*NK + k
    int f = g >> 9;
    int k = g & (NK - 1);
    const float* wf = w + (size_t)f * NDK + k;
    ushort16* ph = wth + (size_t)g * ND;
    ushort16* pl = wtl + (size_t)g * ND;
    float*    pt = wT + (size_t)g * ND;
    float s = 0.f;
#pragma unroll
    for (int dc = 0; dc < 16; ++dc) {
        ushort16 h[4], lo[4];
        float fv[4];
#pragma unroll
        for (int i = 0; i < 4; ++i) {
            float vv = wf[(size_t)(dc * 4 + i) * NK];
            fv[i] = vv;
            s = fmaf(vv, vv, s);
            uint32 hb = bfrne(vv);
            h[i] = (ushort16)(hb >> 16);
            float lf = vv - __uint_as_float(hb);
            lo[i] = (ushort16)(bfrne(lf) >> 16);
        }
        *reinterpret_cast<ushort4*>(ph + dc * 4) = make_ushort4(h[0], h[1], h[2], h[3]);
        *reinterpret_cast<ushort4*>(pl + dc * 4) = make_ushort4(lo[0], lo[1], lo[2], lo[3]);
        *reinterpret_cast<float4*>(pt + dc * 4) =
            make_float4(fv[0], fv[1], fv[2], fv[3]);
    }
    tsq[g] = s + 1024.0f;   // bias: keys positive -> monotone uint compare
}

// ============ kernel B: MFMA argmin assignment (v2: 32 tok/wave + prefetch) ============
// block 256 = 4 independent waves; wave handles 32 tokens (2 groups of 16).
// Grid 1024 blocks -> 16 waves/CU (was 8, grid-starved at 20% occupancy).
// kt-loop software-pipelined: next tile's A fragments + t4 prefetched into
// registers while current tile's MFMAs run (covers L2 latency).
// Distance math / key packing / top-2 margin logic bitwise-identical to v1.
__global__ __launch_bounds__(256) void vq_assign(
    const float* __restrict__ x,
    const ushort16* __restrict__ wth, const ushort16* __restrict__ wtl,
    const float* __restrict__ tsq,
    int* __restrict__ enc, float* __restrict__ counts,
    int* __restrict__ flagcnt, int* __restrict__ flaglist) {
    const int tid = threadIdx.x;
    const int wv  = tid >> 6;
    const int l   = tid & 63;
    const int q   = l >> 4;      // k-quarter / d-chunk selector
    const int col = l & 15;      // token col (B) / k row (A)
    const int blk = blockIdx.x;
    const int f   = blk >> 7;                    // 128 blocks per feature
    const int n0  = (blk & 127) * 128 + wv * 32; // wave's first token

    const float* xf = x + ((size_t)f * NT + n0) * ND;

    // ---- load + split-convert B fragments (32 tokens, resident in regs) ----
    bf16x8 bh[2][2], bl[2][2];
#pragma unroll
    for (int g = 0; g < 2; ++g)
#pragma unroll
        for (int s = 0; s < 2; ++s) {
            const float* p = xf + (size_t)(g * 16 + col) * ND + s * 32 + q * 8;
            f32x4 v0 = *reinterpret_cast<const f32x4*>(p);
            f32x4 v1 = *reinterpret_cast<const f32x4*>(p + 4);
            bf16x8 hh, ll;
#pragma unroll
            for (int j = 0; j < 4; ++j) {
                uint32 hb = bfrne(v0[j]);
                hh[j] = (short)(hb >> 16);
                ll[j] = (short)(bfrne(v0[j] - __uint_as_float(hb)) >> 16);
            }
#pragma unroll
            for (int j = 0; j < 4; ++j) {
                uint32 hb = bfrne(v1[j]);
                hh[4 + j] = (short)(hb >> 16);
                ll[4 + j] = (short)(bfrne(v1[j] - __uint_as_float(hb)) >> 16);
            }
            bh[g][s] = hh;
            bl[g][s] = ll;
        }

    uint32 u1[2], u2[2];
#pragma unroll
    for (int g = 0; g < 2; ++g) { u1[g] = 0xFFFFFFFFu; u2[g] = 0xFFFFFFFFu; }

    const int arow = col * ND + q * 8;
    const ushort16* whf = wth + (size_t)f * NK * ND + arow;
    const ushort16* wlf = wtl + (size_t)f * NK * ND + arow;
    const float*    tf  = tsq + (size_t)f * NK + q * 4;

    // prologue: load kt=0 tile
    bf16x8 ah0 = *reinterpret_cast<const bf16x8*>(whf);
    bf16x8 ah1 = *reinterpret_cast<const bf16x8*>(whf + 32);
    bf16x8 al0 = *reinterpret_cast<const bf16x8*>(wlf);
    bf16x8 al1 = *reinterpret_cast<const bf16x8*>(wlf + 32);
    f32x4  t4  = *reinterpret_cast<const f32x4*>(tf);

    for (int kt = 0; kt < 32; ++kt) {
        // prefetch next tile (wraps to 0 on last iter; result unused)
        const int ktn = (kt + 1) & 31;
        const ushort16* pan = whf + (size_t)ktn * 1024;   // 16*ND ushorts
        const ushort16* pbn = wlf + (size_t)ktn * 1024;
        bf16x8 nah0 = *reinterpret_cast<const bf16x8*>(pan);
        bf16x8 nah1 = *reinterpret_cast<const bf16x8*>(pan + 32);
        bf16x8 nal0 = *reinterpret_cast<const bf16x8*>(pbn);
        bf16x8 nal1 = *reinterpret_cast<const bf16x8*>(pbn + 32);
        f32x4  nt4  = *reinterpret_cast<const f32x4*>(tf + (size_t)ktn * 16);

        uint32 lowb = ((uint32)kt << 4) | ((uint32)q << 2);
#pragma unroll
        for (int g = 0; g < 2; ++g) {
            f32x4 acc = {0.f, 0.f, 0.f, 0.f};
            acc = __builtin_amdgcn_mfma_f32_16x16x32_bf16(ah0, bh[g][0], acc, 0, 0, 0);
            acc = __builtin_amdgcn_mfma_f32_16x16x32_bf16(ah1, bh[g][1], acc, 0, 0, 0);
            acc = __builtin_amdgcn_mfma_f32_16x16x32_bf16(al0, bh[g][0], acc, 0, 0, 0);
            acc = __builtin_amdgcn_mfma_f32_16x16x32_bf16(al1, bh[g][1], acc, 0, 0, 0);
            acc = __builtin_amdgcn_mfma_f32_16x16x32_bf16(ah0, bl[g][0], acc, 0, 0, 0);
            acc = __builtin_amdgcn_mfma_f32_16x16x32_bf16(ah1, bl[g][1], acc, 0, 0, 0);
#pragma unroll
            for (int r = 0; r < 4; ++r) {
                float keyf = fmaf(-2.f, acc[r], t4[r]);          // dist + 1024 > 0
                uint32 key = (__float_as_uint(keyf) & 0xFFFFFE00u) | lowb | (uint32)r;
                uint32 mx = umax_(u1[g], key);
                u1[g] = umin_(u1[g], key);
                u2[g] = umin_(u2[g], mx);
            }
        }
        ah0 = nah0; ah1 = nah1; al0 = nal0; al1 = nal1; t4 = nt4;
    }

    // merge the 4 k-quarters (lanes xor 16, 32): top-2 merge
#pragma unroll
    for (int off = 16; off <= 32; off <<= 1)
#pragma unroll
        for (int g = 0; g < 2; ++g) {
            uint32 p1 = (uint32)__shfl_xor((int)u1[g], off);
            uint32 p2 = (uint32)__shfl_xor((int)u2[g], off);
            uint32 mx = umax_(u1[g], p1);
            u1[g] = umin_(u1[g], p1);
            u2[g] = umin_(umin_(u2[g], p2), mx);
        }

    if (l < 16) {
#pragma unroll
        for (int g = 0; g < 2; ++g) {
            uint32 m1 = u1[g], m2 = u2[g];
            int k = (int)(((m1 >> 4) & 31u) * 16u + ((m1 >> 2) & 3u) * 4u + (m1 & 3u));
            int n = n0 + g * 16 + l;
            enc[(size_t)f * NT + n] = k;
            atomicAdd(&counts[(size_t)f * NK + k], 1.0f);
            float d1 = __uint_as_float(m1 & 0xFFFFFE00u);
            float d2 = __uint_as_float(m2 & 0xFFFFFE00u);
            if (d2 - d1 < MARGIN) {
                int pos = atomicAdd(flagcnt, 1);
                flaglist[pos] = (f << 14) | n;
            }
        }
    }
}

// ============ kernel B2: exact f32 recheck for margin-flagged tokens ============
// block 256 = 4 independent waves; one token per wave.
__global__ __launch_bounds__(256) void vq_fix(const float* __restrict__ x,
                                              const float* __restrict__ w,
                                              const int* __restrict__ flagcnt,
                                              const int* __restrict__ flaglist,
                                              int* __restrict__ enc,
                                              float* __restrict__ counts) {
    const int lane = threadIdx.x & 63;
    const int wv   = threadIdx.x >> 6;
    const int cnt = flagcnt[0];
    const int stride = gridDim.x * 4;
    for (int i = blockIdx.x * 4 + wv; i < cnt; i += stride) {
        int code = flaglist[i];
        int f = code >> 14, n = code & (NT - 1);
        const float* xr = x + ((size_t)f * NT + n) * ND;
        const float* wf = w + (size_t)f * NDK;
        float best = 1e30f;
        int bk = 1 << 30;
#pragma unroll
        for (int j = 0; j < 8; ++j) {
            int k = j * 64 + lane;
            float s = 0.f;
#pragma unroll 8
            for (int d = 0; d < ND; ++d) {
                float diff = xr[d] - wf[(size_t)d * NK + k];
                s = fmaf(diff, diff, s);
            }
            if (s < best) { best = s; bk = k; }   // k ascending -> first-min
        }
#pragma unroll
        for (int off = 1; off < 64; off <<= 1) {
            float ov = __shfl_xor(best, off);
            int   oi = __shfl_xor(bk, off);
            if (ov < best || (ov == best && oi < bk)) { best = ov; bk = oi; }
        }
        if (lane == 0) {
            int kold = enc[(size_t)f * NT + n];
            if (kold != bk) {
                enc[(size_t)f * NT + n] = bk;
                atomicAdd(&counts[(size_t)f * NK + kold], -1.0f);
                atomicAdd(&counts[(size_t)f * NK + bk], 1.0f);
            }
        }
    }
}

// ============ kernel C: per-feature exclusive scan of counts ============
__global__ __launch_bounds__(256) void vq_scan(const float* __restrict__ counts,
                                               int* __restrict__ offs,
                                               int* __restrict__ cursor) {
    __shared__ int wsum[4];
    __shared__ int wpre[4];
    const int f = blockIdx.x, tid = threadIdx.x;
    int c0 = (int)counts[(size_t)f * NK + 2 * tid];
    int c1 = (int)counts[(size_t)f * NK + 2 * tid + 1];
    int pair = c0 + c1;
    int s = pair;
    int lane = tid & 63, wid = tid >> 6;
#pragma unroll
    for (int off = 1; off < 64; off <<= 1) {
        int v = __shfl_up(s, off);
        if (lane >= off) s += v;
    }
    if (lane == 63) wsum[wid] = s;
    __syncthreads();
    if (tid == 0) {
        int r = 0;
#pragma unroll
        for (int i = 0; i < 4; ++i) { wpre[i] = r; r += wsum[i]; }
    }
    __syncthreads();
    int excl = wpre[wid] + s - pair;
    int i0 = f * NK + 2 * tid;
    offs[i0] = excl;        offs[i0 + 1] = excl + c0;
    cursor[i0] = excl;      cursor[i0 + 1] = excl + c0;
}

// ============ kernel D: scatter token ids into cluster-sorted order ============
__global__ __launch_bounds__(256) void vq_scatter(const int* __restrict__ enc,
                                                  int* __restrict__ cursor,
                                                  int* __restrict__ sorted) {
    int i = blockIdx.x * 256 + threadIdx.x;
    if (i < NFN) {
        int f = i >> 14;
        int n = i & (NT - 1);
        int k = enc[i];
        int pos = atomicAdd(&cursor[f * NK + k], 1);
        sorted[(f << 14) + pos] = n;
    }
}

// ============ kernel E: new_cluster_size + smoothed ============
__global__ __launch_bounds__(256) void vq_smooth(const float* __restrict__ ecs,
                                                 const float* __restrict__ counts,
                                                 float* __restrict__ smoothed,
                                                 float* __restrict__ out) {
    __shared__ float wsum[4];
    const int f = blockIdx.x, tid = threadIdx.x;
    float v[2];
    float local = 0.f;
#pragma unroll
    for (int j = 0; j < 2; ++j) {
        int k = tid + j * 256;
        float c = counts[(size_t)f * NK + k];
        float nv = 0.99f * ecs[(size_t)f * NK + k] + 0.01f * c;
        out[NCS_OFF + (size_t)f * NK + k] = nv;
        v[j] = nv;
        local += nv;
    }
#pragma unroll
    for (int off = 32; off > 0; off >>= 1) local += __shfl_xor(local, off);
    if ((tid & 63) == 0) wsum[tid >> 6] = local;
    __syncthreads();
    float n = wsum[0] + wsum[1] + wsum[2] + wsum[3];
#pragma unroll
    for (int j = 0; j < 2; ++j) {
        int k = tid + j * 256;
        smoothed[(size_t)f * NK + k] = (v[j] + 1e-5f) / (n + (float)NK * 1e-5f) * n;
    }
}

// ============ kernel F: equal-work chunk pass over sorted tokens ============
__global__ __launch_bounds__(256) void vq_chunk(const float* __restrict__ x,
                                                const float* __restrict__ wT,
                                                const int* __restrict__ sorted,
                                                const int* __restrict__ enc,
                                                float* __restrict__ dw,
                                                float* __restrict__ loss_sum,
                                                float* __restrict__ out) {
    const int tid  = threadIdx.x;
    const int lane = tid & 63;
    const int cw   = blockIdx.x * 4 + (tid >> 6);   // chunk id 0..2047
    const int f    = cw >> 8;                        // 256 chunks/feature
    const int base = (cw & 255) * 64;

    const float* xf  = x + (((size_t)f << 14) * ND);
    const float* wtf = wT + (size_t)f * NK * ND;
    float* qf = out + (((size_t)f << 14) * ND);
    float* dwf = dw + (size_t)f * NDK + (size_t)lane * NK;

    // each lane pre-loads one (token, k) pair for the chunk
    int n_l = sorted[((size_t)f << 14) + base + lane];
    int k_l = enc[((size_t)f << 14) + n_l];

    float acc = 0.f, l = 0.f;
    int kcur = __shfl(k_l, 0);
#pragma unroll 4
    for (int i = 0; i < 64; ++i) {
        int n = __shfl(n_l, i);
        int k = __shfl(k_l, i);
        float xv = xf[(size_t)n * ND + lane];
        float wc = wtf[(size_t)k * ND + lane];
        qf[(size_t)n * ND + lane] = wc;
        float df = wc - xv;
        l = fmaf(df, df, l);
        if (k != kcur) {               // wave-uniform branch
            atomicAdd(dwf + kcur, acc);
            acc = 0.f;
            kcur = k;
        }
        acc += xv;
    }
    atomicAdd(dwf + kcur, acc);

    // wave loss reduction, one atomic per wave
#pragma unroll
    for (int o = 32; o > 0; o >>= 1) l += __shfl_xor(l, o);
    if (lane == 0) atomicAdd(loss_sum, l);
}

// ============ kernel G: EMA finalize (elementwise) ============
__global__ __launch_bounds__(256) void vq_finalize(const float* __restrict__ dw,
                                                   const float* __restrict__ emaw,
                                                   const float* __restrict__ smoothed,
                                                   float* __restrict__ out) {
    int idx = blockIdx.x * 256 + threadIdx.x;   // 0 .. NF*NDK
    int f = idx >> 15;                           // NDK = 2^15
    int k = idx & (NK - 1);
    float ne = 0.99f * emaw[idx] + 0.01f * dw[idx];
    out[NEMA_OFF + idx] = ne;
    out[NEWW_OFF + idx] = ne / smoothed[(size_t)f * NK + k];
}

// ============ kernel H: loss scalar ============
__global__ void vq_lossfin(const float* __restrict__ loss_sum,
                           float* __restrict__ out) {
    out[LOSS_OFF] = 0.25f * loss_sum[0] / (float)((size_t)NF * NT * ND);
}

extern "C" void kernel_launch(void* const* d_in, const int* in_sizes, int n_in,
                              void* d_out, int out_size, void* d_ws, size_t ws_size,
                              hipStream_t stream) {
    const float* x    = (const float*)d_in[0];
    const float* w    = (const float*)d_in[1];
    const float* ecs  = (const float*)d_in[2];
    const float* emaw = (const float*)d_in[3];
    float* out = (float*)d_out;
    float* ws  = (float*)d_ws;

    float*    counts  = ws + WS_CNT;
    float*    loss    = ws + WS_LOSS;
    int*      flagcnt = (int*)(ws + WS_FLAGC);
    float*    tsq     = ws + WS_T;
    float*    sm      = ws + WS_SM;
    int*      offs    = (int*)(ws + WS_OFFS);
    int*      cursor  = (int*)(ws + WS_CUR);
    int*      enc     = (int*)(ws + WS_ENC);
    int*      sorted  = (int*)(ws + WS_SORT);
    int*      flagl   = (int*)(ws + WS_FLAGL);
    ushort16* wth     = (ushort16*)(ws + WS_WTH);
    ushort16* wtl     = (ushort16*)(ws + WS_WTL);
    float*    wT      = ws + WS_WT;
    float*    dw      = ws + WS_DW;

    // zero counts + loss + flagcnt, and dw accumulator (capture-safe)
    hipMemsetAsync(counts, 0, (size_t)4112 * sizeof(float), stream);
    hipMemsetAsync(dw, 0, (size_t)NF * NDK * sizeof(float), stream);

    vq_prep_w<<<16, 256, 0, stream>>>(w, wth, wtl, wT, tsq);
    vq_assign<<<NFN / 128, 256, 0, stream>>>(x, wth, wtl, tsq, enc, counts,
                                             flagcnt, flagl);
    vq_fix<<<2048, 256, 0, stream>>>(x, w, flagcnt, flagl, enc, counts);
    vq_scan<<<NF, 256, 0, stream>>>(counts, offs, cursor);
    vq_scatter<<<NFN / 256, 256, 0, stream>>>(enc, cursor, sorted);
    vq_smooth<<<NF, 256, 0, stream>>>(ecs, counts, sm, out);
    vq_chunk<<<512, 256, 0, stream>>>(x, wT, sorted, enc, dw, loss, out);
    vq_finalize<<<NF * NDK / 256, 256, 0, stream>>>(dw, emaw, sm, out);
    vq_lossfin<<<1, 1, 0, stream>>>(loss, out);
}

// Round 12
// 192.685 us; speedup vs baseline: 1.1142x; 1.1142x over previous
//
#include <hip/hip_runtime.h>
#include <cstddef>

#define NF 8
#define NT 16384
#define ND 64
#define NK 512
#define NDK (ND * NK)      // 32768
#define NFN (NF * NT)      // 131072
#define MARGIN 0.125f

typedef __attribute__((ext_vector_type(8))) short bf16x8;
typedef __attribute__((ext_vector_type(4))) float f32x4;
typedef unsigned int uint32;
typedef unsigned short ushort16;

// ---- workspace layout (float units) ----
static const size_t WS_CNT   = 0;        // counts      : 4096
static const size_t WS_LOSS  = 4096;     // loss accum  : 1
static const size_t WS_FLAGC = 4097;     // flag count  : 1 int
static const size_t WS_T     = 4112;     // tsq + 1024  : 4096
static const size_t WS_SM    = 8208;     // smoothed    : 4096
static const size_t WS_OFFS  = 12304;    // offsets     : 4096 ints
static const size_t WS_CUR   = 16400;    // cursors     : 4096 ints
static const size_t WS_ENC   = 20496;    // enc idx     : NFN ints
static const size_t WS_SORT  = 151568;   // sorted tok  : NFN ints
static const size_t WS_FLAGL = 282640;   // flag list   : NFN ints
static const size_t WS_WTH   = 413712;   // w^T hi bf16 : 131072 floats
static const size_t WS_WTL   = 544784;   // w^T lo bf16 : 131072 floats
static const size_t WS_WT    = 675856;   // w^T f32 [f,k,d] : 262144 floats
static const size_t WS_DW    = 938000;   // dw accum    : 262144 floats

// ---- output layout (float units) ----
static const size_t LOSS_OFF = (size_t)NF * NT * ND;        // 8388608
static const size_t NEWW_OFF = LOSS_OFF + 1;                // 8388609
static const size_t NCS_OFF  = NEWW_OFF + (size_t)NF * NDK; // 8650753
static const size_t NEMA_OFF = NCS_OFF + (size_t)NF * NK;   // 8654849

__device__ inline uint32 bfrne(float f) {   // RNE bf16, as hi-16 bits of f32
    uint32 u = __float_as_uint(f);
    return (u + 0x7FFFu + ((u >> 16) & 1u)) & 0xFFFF0000u;
}
__device__ inline uint32 umin_(uint32 a, uint32 b) { return a < b ? a : b; }
__device__ inline uint32 umax_(uint32 a, uint32 b) { return a > b ? a : b; }

// ============ kernel A: W -> wt_hi/wt_lo bf16 [f,k,d] + wT f32 + tsq+1024 ============
__global__ __launch_bounds__(256) void vq_prep_w(const float* __restrict__ w,
                                                 ushort16* __restrict__ wth,
                                                 ushort16* __restrict__ wtl,
                                                 float* __restrict__ wT,
                                                 float* __restrict__ tsq) {
    int g = blockIdx.x * 256 + threadIdx.x;   // f*NK + k
    int f = g >> 9;
    int k = g & (NK - 1);
    const float* wf = w + (size_t)f * NDK + k;
    ushort16* ph = wth + (size_t)g * ND;
    ushort16* pl = wtl + (size_t)g * ND;
    float*    pt = wT + (size_t)g * ND;
    float s = 0.f;
#pragma unroll
    for (int dc = 0; dc < 16; ++dc) {
        ushort16 h[4], lo[4];
        float fv[4];
#pragma unroll
        for (int i = 0; i < 4; ++i) {
            float vv = wf[(size_t)(dc * 4 + i) * NK];
            fv[i] = vv;
            s = fmaf(vv, vv, s);
            uint32 hb = bfrne(vv);
            h[i] = (ushort16)(hb >> 16);
            float lf = vv - __uint_as_float(hb);
            lo[i] = (ushort16)(bfrne(lf) >> 16);
        }
        *reinterpret_cast<ushort4*>(ph + dc * 4) = make_ushort4(h[0], h[1], h[2], h[3]);
        *reinterpret_cast<ushort4*>(pl + dc * 4) = make_ushort4(lo[0], lo[1], lo[2], lo[3]);
        *reinterpret_cast<float4*>(pt + dc * 4) =
            make_float4(fv[0], fv[1], fv[2], fv[3]);
    }
    tsq[g] = s + 1024.0f;   // bias: keys positive -> monotone uint compare
}

// ============ kernel B: MFMA argmin assignment (v3: K-split, 64 tok/wave) ============
// Block 256 = 4 waves = 2 token-groups x 2 K-halves. Each wave: 64 tokens
// (4 groups of 16, v1 intensity: 24 MFMA per kt-tile) over 16 of the 32
// kt-tiles. The two K-half waves merge exact top-2 via LDS. Grid 1024
// blocks -> 16 waves/CU (2x v1) at v1's total A-tile traffic.
// Key packing / margin semantics identical to v1/v2.
__global__ __launch_bounds__(256) void vq_assign(
    const float* __restrict__ x,
    const ushort16* __restrict__ wth, const ushort16* __restrict__ wtl,
    const float* __restrict__ tsq,
    int* __restrict__ enc, float* __restrict__ counts,
    int* __restrict__ flagcnt, int* __restrict__ flaglist) {
    __shared__ uint32 su1[2][128];
    __shared__ uint32 su2[2][128];

    const int tid = threadIdx.x;
    const int wv  = tid >> 6;
    const int tg  = wv >> 1;     // token-group half (0/1)
    const int kh  = wv & 1;      // K half (0/1)
    const int l   = tid & 63;
    const int q   = l >> 4;      // k-quarter / d-chunk selector
    const int col = l & 15;      // token col (B) / k row (A)
    const int blk = blockIdx.x;
    const int f   = blk >> 7;                    // 128 blocks per feature
    const int nb  = (blk & 127) * 128;           // block's first token
    const int n0  = nb + tg * 64;                // wave's first token

    const float* xf = x + ((size_t)f * NT + n0) * ND;

    // ---- load + split-convert B fragments (64 tokens, resident in regs) ----
    bf16x8 bh[4][2], bl[4][2];
#pragma unroll
    for (int g = 0; g < 4; ++g)
#pragma unroll
        for (int s = 0; s < 2; ++s) {
            const float* p = xf + (size_t)(g * 16 + col) * ND + s * 32 + q * 8;
            f32x4 v0 = *reinterpret_cast<const f32x4*>(p);
            f32x4 v1 = *reinterpret_cast<const f32x4*>(p + 4);
            bf16x8 hh, ll;
#pragma unroll
            for (int j = 0; j < 4; ++j) {
                uint32 hb = bfrne(v0[j]);
                hh[j] = (short)(hb >> 16);
                ll[j] = (short)(bfrne(v0[j] - __uint_as_float(hb)) >> 16);
            }
#pragma unroll
            for (int j = 0; j < 4; ++j) {
                uint32 hb = bfrne(v1[j]);
                hh[4 + j] = (short)(hb >> 16);
                ll[4 + j] = (short)(bfrne(v1[j] - __uint_as_float(hb)) >> 16);
            }
            bh[g][s] = hh;
            bl[g][s] = ll;
        }

    uint32 u1[4], u2[4];
#pragma unroll
    for (int g = 0; g < 4; ++g) { u1[g] = 0xFFFFFFFFu; u2[g] = 0xFFFFFFFFu; }

    const ushort16* whf = wth + (size_t)f * NK * ND;
    const ushort16* wlf = wtl + (size_t)f * NK * ND;
    const float* tf = tsq + (size_t)f * NK;
    const int arow = col * ND + q * 8;

    for (int ktl = 0; ktl < 16; ++ktl) {
        const int kt = kh * 16 + ktl;            // global kt tile
        const ushort16* pa = whf + (size_t)kt * 1024 + arow;
        const ushort16* pb = wlf + (size_t)kt * 1024 + arow;
        bf16x8 ah0 = *reinterpret_cast<const bf16x8*>(pa);
        bf16x8 ah1 = *reinterpret_cast<const bf16x8*>(pa + 32);
        bf16x8 al0 = *reinterpret_cast<const bf16x8*>(pb);
        bf16x8 al1 = *reinterpret_cast<const bf16x8*>(pb + 32);
        f32x4 t4 = *reinterpret_cast<const f32x4*>(tf + kt * 16 + q * 4);
        uint32 lowb = ((uint32)kt << 4) | ((uint32)q << 2);
#pragma unroll
        for (int g = 0; g < 4; ++g) {
            f32x4 acc = {0.f, 0.f, 0.f, 0.f};
            acc = __builtin_amdgcn_mfma_f32_16x16x32_bf16(ah0, bh[g][0], acc, 0, 0, 0);
            acc = __builtin_amdgcn_mfma_f32_16x16x32_bf16(ah1, bh[g][1], acc, 0, 0, 0);
            acc = __builtin_amdgcn_mfma_f32_16x16x32_bf16(al0, bh[g][0], acc, 0, 0, 0);
            acc = __builtin_amdgcn_mfma_f32_16x16x32_bf16(al1, bh[g][1], acc, 0, 0, 0);
            acc = __builtin_amdgcn_mfma_f32_16x16x32_bf16(ah0, bl[g][0], acc, 0, 0, 0);
            acc = __builtin_amdgcn_mfma_f32_16x16x32_bf16(ah1, bl[g][1], acc, 0, 0, 0);
#pragma unroll
            for (int r = 0; r < 4; ++r) {
                float keyf = fmaf(-2.f, acc[r], t4[r]);          // dist + 1024 > 0
                uint32 key = (__float_as_uint(keyf) & 0xFFFFFE00u) | lowb | (uint32)r;
                uint32 mx = umax_(u1[g], key);
                u1[g] = umin_(u1[g], key);
                u2[g] = umin_(u2[g], mx);
            }
        }
    }

    // merge the 4 k-quarters (lanes xor 16, 32): top-2 merge
#pragma unroll
    for (int off = 16; off <= 32; off <<= 1)
#pragma unroll
        for (int g = 0; g < 4; ++g) {
            uint32 p1 = (uint32)__shfl_xor((int)u1[g], off);
            uint32 p2 = (uint32)__shfl_xor((int)u2[g], off);
            uint32 mx = umax_(u1[g], p1);
            u1[g] = umin_(u1[g], p1);
            u2[g] = umin_(umin_(u2[g], p2), mx);
        }

    // stash this wave's K-half top-2 into LDS
    if (l < 16) {
#pragma unroll
        for (int g = 0; g < 4; ++g) {
            su1[kh][tg * 64 + g * 16 + l] = u1[g];
            su2[kh][tg * 64 + g * 16 + l] = u2[g];
        }
    }
    __syncthreads();

    // merge K-halves; one thread per token
    if (tid < 128) {
        uint32 a1 = su1[0][tid], a2 = su2[0][tid];
        uint32 b1 = su1[1][tid], b2 = su2[1][tid];
        uint32 m1 = umin_(a1, b1);
        uint32 m2 = umin_(umin_(a2, b2), umax_(a1, b1));
        int k = (int)(((m1 >> 4) & 31u) * 16u + ((m1 >> 2) & 3u) * 4u + (m1 & 3u));
        int n = nb + tid;
        enc[(size_t)f * NT + n] = k;
        atomicAdd(&counts[(size_t)f * NK + k], 1.0f);
        float d1 = __uint_as_float(m1 & 0xFFFFFE00u);
        float d2 = __uint_as_float(m2 & 0xFFFFFE00u);
        if (d2 - d1 < MARGIN) {
            int pos = atomicAdd(flagcnt, 1);
            flaglist[pos] = (f << 14) | n;
        }
    }
}

// ============ kernel B2: exact f32 recheck for margin-flagged tokens ============
// block 256 = 4 independent waves; one token per wave.
__global__ __launch_bounds__(256) void vq_fix(const float* __restrict__ x,
                                              const float* __restrict__ w,
                                              const int* __restrict__ flagcnt,
                                              const int* __restrict__ flaglist,
                                              int* __restrict__ enc,
                                              float* __restrict__ counts) {
    const int lane = threadIdx.x & 63;
    const int wv   = threadIdx.x >> 6;
    const int cnt = flagcnt[0];
    const int stride = gridDim.x * 4;
    for (int i = blockIdx.x * 4 + wv; i < cnt; i += stride) {
        int code = flaglist[i];
        int f = code >> 14, n = code & (NT - 1);
        const float* xr = x + ((size_t)f * NT + n) * ND;
        const float* wf = w + (size_t)f * NDK;
        float best = 1e30f;
        int bk = 1 << 30;
#pragma unroll
        for (int j = 0; j < 8; ++j) {
            int k = j * 64 + lane;
            float s = 0.f;
#pragma unroll 8
            for (int d = 0; d < ND; ++d) {
                float diff = xr[d] - wf[(size_t)d * NK + k];
                s = fmaf(diff, diff, s);
            }
            if (s < best) { best = s; bk = k; }   // k ascending -> first-min
        }
#pragma unroll
        for (int off = 1; off < 64; off <<= 1) {
            float ov = __shfl_xor(best, off);
            int   oi = __shfl_xor(bk, off);
            if (ov < best || (ov == best && oi < bk)) { best = ov; bk = oi; }
        }
        if (lane == 0) {
            int kold = enc[(size_t)f * NT + n];
            if (kold != bk) {
                enc[(size_t)f * NT + n] = bk;
                atomicAdd(&counts[(size_t)f * NK + kold], -1.0f);
                atomicAdd(&counts[(size_t)f * NK + bk], 1.0f);
            }
        }
    }
}

// ============ kernel C: per-feature exclusive scan of counts ============
__global__ __launch_bounds__(256) void vq_scan(const float* __restrict__ counts,
                                               int* __restrict__ offs,
                                               int* __restrict__ cursor) {
    __shared__ int wsum[4];
    __shared__ int wpre[4];
    const int f = blockIdx.x, tid = threadIdx.x;
    int c0 = (int)counts[(size_t)f * NK + 2 * tid];
    int c1 = (int)counts[(size_t)f * NK + 2 * tid + 1];
    int pair = c0 + c1;
    int s = pair;
    int lane = tid & 63, wid = tid >> 6;
#pragma unroll
    for (int off = 1; off < 64; off <<= 1) {
        int v = __shfl_up(s, off);
        if (lane >= off) s += v;
    }
    if (lane == 63) wsum[wid] = s;
    __syncthreads();
    if (tid == 0) {
        int r = 0;
#pragma unroll
        for (int i = 0; i < 4; ++i) { wpre[i] = r; r += wsum[i]; }
    }
    __syncthreads();
    int excl = wpre[wid] + s - pair;
    int i0 = f * NK + 2 * tid;
    offs[i0] = excl;        offs[i0 + 1] = excl + c0;
    cursor[i0] = excl;      cursor[i0 + 1] = excl + c0;
}

// ============ kernel D: scatter token ids into cluster-sorted order ============
__global__ __launch_bounds__(256) void vq_scatter(const int* __restrict__ enc,
                                                  int* __restrict__ cursor,
                                                  int* __restrict__ sorted) {
    int i = blockIdx.x * 256 + threadIdx.x;
    if (i < NFN) {
        int f = i >> 14;
        int n = i & (NT - 1);
        int k = enc[i];
        int pos = atomicAdd(&cursor[f * NK + k], 1);
        sorted[(f << 14) + pos] = n;
    }
}

// ============ kernel E: new_cluster_size + smoothed ============
__global__ __launch_bounds__(256) void vq_smooth(const float* __restrict__ ecs,
                                                 const float* __restrict__ counts,
                                                 float* __restrict__ smoothed,
                                                 float* __restrict__ out) {
    __shared__ float wsum[4];
    const int f = blockIdx.x, tid = threadIdx.x;
    float v[2];
    float local = 0.f;
#pragma unroll
    for (int j = 0; j < 2; ++j) {
        int k = tid + j * 256;
        float c = counts[(size_t)f * NK + k];
        float nv = 0.99f * ecs[(size_t)f * NK + k] + 0.01f * c;
        out[NCS_OFF + (size_t)f * NK + k] = nv;
        v[j] = nv;
        local += nv;
    }
#pragma unroll
    for (int off = 32; off > 0; off >>= 1) local += __shfl_xor(local, off);
    if ((tid & 63) == 0) wsum[tid >> 6] = local;
    __syncthreads();
    float n = wsum[0] + wsum[1] + wsum[2] + wsum[3];
#pragma unroll
    for (int j = 0; j < 2; ++j) {
        int k = tid + j * 256;
        smoothed[(size_t)f * NK + k] = (v[j] + 1e-5f) / (n + (float)NK * 1e-5f) * n;
    }
}

// ============ kernel F: equal-work chunk pass over sorted tokens ============
__global__ __launch_bounds__(256) void vq_chunk(const float* __restrict__ x,
                                                const float* __restrict__ wT,
                                                const int* __restrict__ sorted,
                                                const int* __restrict__ enc,
                                                float* __restrict__ dw,
                                                float* __restrict__ loss_sum,
                                                float* __restrict__ out) {
    const int tid  = threadIdx.x;
    const int lane = tid & 63;
    const int cw   = blockIdx.x * 4 + (tid >> 6);   // chunk id 0..2047
    const int f    = cw >> 8;                        // 256 chunks/feature
    const int base = (cw & 255) * 64;

    const float* xf  = x + (((size_t)f << 14) * ND);
    const float* wtf = wT + (size_t)f * NK * ND;
    float* qf = out + (((size_t)f << 14) * ND);
    float* dwf = dw + (size_t)f * NDK + (size_t)lane * NK;

    // each lane pre-loads one (token, k) pair for the chunk
    int n_l = sorted[((size_t)f << 14) + base + lane];
    int k_l = enc[((size_t)f << 14) + n_l];

    float acc = 0.f, l = 0.f;
    int kcur = __shfl(k_l, 0);
#pragma unroll 4
    for (int i = 0; i < 64; ++i) {
        int n = __shfl(n_l, i);
        int k = __shfl(k_l, i);
        float xv = xf[(size_t)n * ND + lane];
        float wc = wtf[(size_t)k * ND + lane];
        qf[(size_t)n * ND + lane] = wc;
        float df = wc - xv;
        l = fmaf(df, df, l);
        if (k != kcur) {               // wave-uniform branch
            atomicAdd(dwf + kcur, acc);
            acc = 0.f;
            kcur = k;
        }
        acc += xv;
    }
    atomicAdd(dwf + kcur, acc);

    // wave loss reduction, one atomic per wave
#pragma unroll
    for (int o = 32; o > 0; o >>= 1) l += __shfl_xor(l, o);
    if (lane == 0) atomicAdd(loss_sum, l);
}

// ============ kernel G: EMA finalize (elementwise) ============
__global__ __launch_bounds__(256) void vq_finalize(const float* __restrict__ dw,
                                                   const float* __restrict__ emaw,
                                                   const float* __restrict__ smoothed,
                                                   float* __restrict__ out) {
    int idx = blockIdx.x * 256 + threadIdx.x;   // 0 .. NF*NDK
    int f = idx >> 15;                           // NDK = 2^15
    int k = idx & (NK - 1);
    float ne = 0.99f * emaw[idx] + 0.01f * dw[idx];
    out[NEMA_OFF + idx] = ne;
    out[NEWW_OFF + idx] = ne / smoothed[(size_t)f * NK + k];
}

// ============ kernel H: loss scalar ============
__global__ void vq_lossfin(const float* __restrict__ loss_sum,
                           float* __restrict__ out) {
    out[LOSS_OFF] = 0.25f * loss_sum[0] / (float)((size_t)NF * NT * ND);
}

extern "C" void kernel_launch(void* const* d_in, const int* in_sizes, int n_in,
                              void* d_out, int out_size, void* d_ws, size_t ws_size,
                              hipStream_t stream) {
    const float* x    = (const float*)d_in[0];
    const float* w    = (const float*)d_in[1];
    const float* ecs  = (const float*)d_in[2];
    const float* emaw = (const float*)d_in[3];
    float* out = (float*)d_out;
    float* ws  = (float*)d_ws;

    float*    counts  = ws + WS_CNT;
    float*    loss    = ws + WS_LOSS;
    int*      flagcnt = (int*)(ws + WS_FLAGC);
    float*    tsq     = ws + WS_T;
    float*    sm      = ws + WS_SM;
    int*      offs    = (int*)(ws + WS_OFFS);
    int*      cursor  = (int*)(ws + WS_CUR);
    int*      enc     = (int*)(ws + WS_ENC);
    int*      sorted  = (int*)(ws + WS_SORT);
    int*      flagl   = (int*)(ws + WS_FLAGL);
    ushort16* wth     = (ushort16*)(ws + WS_WTH);
    ushort16* wtl     = (ushort16*)(ws + WS_WTL);
    float*    wT      = ws + WS_WT;
    float*    dw      = ws + WS_DW;

    // zero counts + loss + flagcnt, and dw accumulator (capture-safe)
    hipMemsetAsync(counts, 0, (size_t)4112 * sizeof(float), stream);
    hipMemsetAsync(dw, 0, (size_t)NF * NDK * sizeof(float), stream);

    vq_prep_w<<<16, 256, 0, stream>>>(w, wth, wtl, wT, tsq);
    vq_assign<<<NFN / 128, 256, 0, stream>>>(x, wth, wtl, tsq, enc, counts,
                                             flagcnt, flagl);
    vq_fix<<<2048, 256, 0, stream>>>(x, w, flagcnt, flagl, enc, counts);
    vq_scan<<<NF, 256, 0, stream>>>(counts, offs, cursor);
    vq_scatter<<<NFN / 256, 256, 0, stream>>>(enc, cursor, sorted);
    vq_smooth<<<NF, 256, 0, stream>>>(ecs, counts, sm, out);
    vq_chunk<<<512, 256, 0, stream>>>(x, wT, sorted, enc, dw, loss, out);
    vq_finalize<<<NF * NDK / 256, 256, 0, stream>>>(dw, emaw, sm, out);
    vq_lossfin<<<1, 1, 0, stream>>>(loss, out);
}